// Round 1
// baseline (3342.577 us; speedup 1.0000x reference)
//
#include <hip/hip_runtime.h>

constexpr int N  = 50000;
constexpr int E  = 1600000;
constexpr int FIN = 16;
constexpr int T  = 8;
constexpr int H  = 64;
constexpr int C  = 10;

// ---------------- degree + histogram ----------------
__global__ void deg_count_kernel(const int* __restrict__ ei, const float* __restrict__ w,
                                 float* __restrict__ deg, int* __restrict__ counts) {
  int e = blockIdx.x * blockDim.x + threadIdx.x;
  if (e >= E) return;
  int d = ei[E + e];
  atomicAdd(&deg[d], w[e]);
  atomicAdd(&counts[d], 1);
}

__global__ void dinv_kernel(float* deg) {
  int n = blockIdx.x * blockDim.x + threadIdx.x;
  if (n >= N) return;
  deg[n] = rsqrtf(deg[n] + 1.0f);  // +1 = self-loop weight
}

// ---------------- exclusive scan (single block, 1024 threads) ----------------
__global__ void scan_kernel(const int* __restrict__ counts, int* __restrict__ rowptr) {
  __shared__ int wsum[16];
  __shared__ int carry_s;
  int tid = threadIdx.x;
  if (tid == 0) carry_s = 0;
  __syncthreads();
  for (int base = 0; base < N; base += 1024) {
    int i = base + tid;
    int v = (i < N) ? counts[i] : 0;
    int x = v;
    #pragma unroll
    for (int off = 1; off < 64; off <<= 1) {
      int y = __shfl_up(x, off, 64);
      if ((tid & 63) >= off) x += y;
    }
    if ((tid & 63) == 63) wsum[tid >> 6] = x;
    __syncthreads();
    if (tid < 16) {
      int wv = wsum[tid];
      #pragma unroll
      for (int off = 1; off < 16; off <<= 1) {
        int y = __shfl_up(wv, off, 16);
        if (tid >= off) wv += y;
      }
      wsum[tid] = wv;
    }
    __syncthreads();
    int carry = carry_s;
    int waveoff = (tid >> 6) ? wsum[(tid >> 6) - 1] : 0;
    int inc = x + waveoff + carry;
    if (i < N) rowptr[i + 1] = inc;
    __syncthreads();
    if (tid == 1023) carry_s = inc;
    __syncthreads();
  }
  if (tid == 0) rowptr[0] = 0;
}

// ---------------- CSR fill ----------------
__global__ void fill_kernel(const int* __restrict__ ei, const float* __restrict__ w,
                            const float* __restrict__ dinv, const int* __restrict__ rowptr,
                            int* __restrict__ fill, int* __restrict__ csr_src,
                            float* __restrict__ csr_norm) {
  int e = blockIdx.x * blockDim.x + threadIdx.x;
  if (e >= E) return;
  int s = ei[e], d = ei[E + e];
  int pos = rowptr[d] + atomicAdd(&fill[d], 1);
  csr_src[pos] = s;
  csr_norm[pos] = dinv[s] * w[e] * dinv[d];
}

// ---------------- aggregate raw input: Xagg = Ahat @ X  (128 ch = FIN*T) ----------------
__global__ void agg_x_kernel(const float* __restrict__ x, const float* __restrict__ dinv,
                             const int* __restrict__ rowptr, const int* __restrict__ csr_src,
                             const float* __restrict__ csr_norm, float* __restrict__ xagg) {
  int n = blockIdx.x;
  int c = threadIdx.x;  // 0..127
  float di = dinv[n];
  float a = di * di * x[(size_t)n * 128 + c];
  int e0 = rowptr[n], e1 = rowptr[n + 1];
  for (int e = e0; e < e1; ++e) {
    int s = csr_src[e];
    float nm = csr_norm[e];
    a += nm * x[(size_t)s * 128 + c];
  }
  xagg[(size_t)n * 128 + c] = a;
}

// ---------------- layer1: h1 = relu(Xagg[:, :, t] @ W1 + b1); G2 = h1 @ W2 ----------------
__global__ void layer1_kernel(const float* __restrict__ xagg, const float* __restrict__ W1,
                              const float* __restrict__ b1, const float* __restrict__ W2,
                              float* __restrict__ G2, int t) {
  __shared__ float w2s[H * H];
  __shared__ float h1s[4][H];
  int tid = threadIdx.x;
  for (int i = tid; i < H * H; i += 256) w2s[i] = W2[i];
  int wv = tid >> 6, j = tid & 63;
  int n = blockIdx.x * 4 + wv;
  const float* xa = xagg + (size_t)n * 128;
  float a = b1[j];
  #pragma unroll
  for (int f = 0; f < FIN; ++f) a += xa[f * 8 + t] * W1[f * H + j];
  h1s[wv][j] = fmaxf(a, 0.0f);
  __syncthreads();
  float g = 0.0f;
  #pragma unroll
  for (int k = 0; k < H; ++k) g += h1s[wv][k] * w2s[k * H + j];
  G2[(size_t)n * H + j] = g;
}

// ---------------- conv stage: h = relu(Ahat@Gin + b); Gout (+)= h @ Wnext ----------------
template<bool ACCUM>
__global__ void conv_kernel(const float* __restrict__ Gin, const float* __restrict__ dinv,
                            const int* __restrict__ rowptr, const int* __restrict__ csr_src,
                            const float* __restrict__ csr_norm, const float* __restrict__ b,
                            const float* __restrict__ Wnext, float* __restrict__ Gout) {
  __shared__ float ws[H * H];
  __shared__ float hs[4][H];
  int tid = threadIdx.x;
  for (int i = tid; i < H * H; i += 256) ws[i] = Wnext[i];
  int wv = tid >> 6, j = tid & 63;
  int n = blockIdx.x * 4 + wv;
  float di = dinv[n];
  float a = b[j] + di * di * Gin[(size_t)n * H + j];
  int e0 = rowptr[n], e1 = rowptr[n + 1];
  for (int e = e0; e < e1; ++e) {
    int s = csr_src[e];
    float nm = csr_norm[e];
    a += nm * Gin[(size_t)s * H + j];
  }
  hs[wv][j] = fmaxf(a, 0.0f);
  __syncthreads();
  float g = 0.0f;
  #pragma unroll
  for (int k = 0; k < H; ++k) g += hs[wv][k] * ws[k * H + j];
  if (ACCUM) Gout[(size_t)n * H + j] += g;
  else       Gout[(size_t)n * H + j]  = g;
}

// ---------------- head: hf = relu(acc + bseq); out = hf @ Wcls + bcls ----------------
__global__ void final_kernel(const float* __restrict__ acc, const float* __restrict__ bseq,
                             const float* __restrict__ Wcls, const float* __restrict__ bcls,
                             float* __restrict__ out) {
  __shared__ float hs[4][H];
  int tid = threadIdx.x;
  int wv = tid >> 6, j = tid & 63;
  int n = blockIdx.x * 4 + wv;
  hs[wv][j] = fmaxf(acc[(size_t)n * H + j] + bseq[j], 0.0f);
  __syncthreads();
  if (j < C) {
    float o = bcls[j];
    #pragma unroll
    for (int k = 0; k < H; ++k) o += hs[wv][k] * Wcls[k * C + j];
    out[(size_t)n * C + j] = o;
  }
}

extern "C" void kernel_launch(void* const* d_in, const int* in_sizes, int n_in,
                              void* d_out, int out_size, void* d_ws, size_t ws_size,
                              hipStream_t stream) {
  const float* x    = (const float*)d_in[0];
  const int*   ei   = (const int*)  d_in[1];
  const float* w    = (const float*)d_in[2];
  const float* W1   = (const float*)d_in[3];
  const float* b1   = (const float*)d_in[4];
  const float* W2   = (const float*)d_in[5];
  const float* b2   = (const float*)d_in[6];
  const float* W3   = (const float*)d_in[7];
  const float* b3   = (const float*)d_in[8];
  const float* Wseq = (const float*)d_in[9];
  const float* bseq = (const float*)d_in[10];
  const float* Wcls = (const float*)d_in[11];
  const float* bcls = (const float*)d_in[12];
  float* out = (float*)d_out;

  char* p = (char*)d_ws;
  auto alloc = [&](size_t bytes) -> char* {
    char* r = p; p += (bytes + 255) & ~(size_t)255; return r;
  };
  float* deg     = (float*)alloc((size_t)N * 4);        // becomes dinv
  int*   counts  = (int*)  alloc((size_t)N * 4);
  int*   fillc   = (int*)  alloc((size_t)N * 4);
  int*   rowptr  = (int*)  alloc((size_t)(N + 1) * 4);
  int*   csr_src = (int*)  alloc((size_t)E * 4);
  float* csr_nrm = (float*)alloc((size_t)E * 4);
  float* xagg    = (float*)alloc((size_t)N * 128 * 4);
  float* GA      = (float*)alloc((size_t)N * H * 4);
  float* GB      = (float*)alloc((size_t)N * H * 4);
  float* acc     = (float*)alloc((size_t)N * H * 4);

  hipMemsetAsync(deg,    0, (size_t)N * 4, stream);
  hipMemsetAsync(counts, 0, (size_t)N * 4, stream);
  hipMemsetAsync(fillc,  0, (size_t)N * 4, stream);
  hipMemsetAsync(acc,    0, (size_t)N * H * 4, stream);

  deg_count_kernel<<<(E + 255) / 256, 256, 0, stream>>>(ei, w, deg, counts);
  dinv_kernel<<<(N + 255) / 256, 256, 0, stream>>>(deg);
  scan_kernel<<<1, 1024, 0, stream>>>(counts, rowptr);
  fill_kernel<<<(E + 255) / 256, 256, 0, stream>>>(ei, w, deg, rowptr, fillc, csr_src, csr_nrm);
  agg_x_kernel<<<N, 128, 0, stream>>>(x, deg, rowptr, csr_src, csr_nrm, xagg);

  for (int t = 0; t < T; ++t) {
    layer1_kernel<<<N / 4, 256, 0, stream>>>(xagg, W1, b1, W2, GA, t);
    conv_kernel<false><<<N / 4, 256, 0, stream>>>(GA, deg, rowptr, csr_src, csr_nrm, b2, W3, GB);
    conv_kernel<true ><<<N / 4, 256, 0, stream>>>(GB, deg, rowptr, csr_src, csr_nrm, b3,
                                                  Wseq + (size_t)t * H * H, acc);
  }
  final_kernel<<<N / 4, 256, 0, stream>>>(acc, bseq, Wcls, bcls, out);
}

// Round 2
// 1533.384 us; speedup vs baseline: 2.1799x; 2.1799x over previous
//
#include <hip/hip_runtime.h>

constexpr int N  = 50000;
constexpr int E  = 1600000;
constexpr int T  = 8;
constexpr int H  = 64;
constexpr int C  = 10;

// ---------------- degree + histogram ----------------
__global__ void deg_count_kernel(const int* __restrict__ ei, const float* __restrict__ w,
                                 float* __restrict__ deg, int* __restrict__ counts) {
  int e = blockIdx.x * blockDim.x + threadIdx.x;
  if (e >= E) return;
  int d = ei[E + e];
  atomicAdd(&deg[d], w[e]);
  atomicAdd(&counts[d], 1);
}

__global__ void dinv_kernel(float* deg) {
  int n = blockIdx.x * blockDim.x + threadIdx.x;
  if (n >= N) return;
  deg[n] = rsqrtf(deg[n] + 1.0f);  // +1 = self-loop weight
}

// ---------------- exclusive scan (single block, 1024 threads) ----------------
__global__ void scan_kernel(const int* __restrict__ counts, int* __restrict__ rowptr) {
  __shared__ int wsum[16];
  __shared__ int carry_s;
  int tid = threadIdx.x;
  if (tid == 0) carry_s = 0;
  __syncthreads();
  for (int base = 0; base < N; base += 1024) {
    int i = base + tid;
    int v = (i < N) ? counts[i] : 0;
    int x = v;
    #pragma unroll
    for (int off = 1; off < 64; off <<= 1) {
      int y = __shfl_up(x, off, 64);
      if ((tid & 63) >= off) x += y;
    }
    if ((tid & 63) == 63) wsum[tid >> 6] = x;
    __syncthreads();
    if (tid < 16) {
      int wv = wsum[tid];
      #pragma unroll
      for (int off = 1; off < 16; off <<= 1) {
        int y = __shfl_up(wv, off, 16);
        if (tid >= off) wv += y;
      }
      wsum[tid] = wv;
    }
    __syncthreads();
    int carry = carry_s;
    int waveoff = (tid >> 6) ? wsum[(tid >> 6) - 1] : 0;
    int inc = x + waveoff + carry;
    if (i < N) rowptr[i + 1] = inc;
    __syncthreads();
    if (tid == 1023) carry_s = inc;
    __syncthreads();
  }
  if (tid == 0) rowptr[0] = 0;
}

// ---------------- CSR fill ----------------
__global__ void fill_kernel(const int* __restrict__ ei, const float* __restrict__ w,
                            const float* __restrict__ dinv, const int* __restrict__ rowptr,
                            int* __restrict__ fill, int* __restrict__ csr_src,
                            float* __restrict__ csr_norm) {
  int e = blockIdx.x * blockDim.x + threadIdx.x;
  if (e >= E) return;
  int s = ei[e], d = ei[E + e];
  int pos = rowptr[d] + atomicAdd(&fill[d], 1);
  csr_src[pos] = s;
  csr_norm[pos] = dinv[s] * w[e] * dinv[d];
}

// ---------------- xagg = Ahat @ X (128 ch), wave/node, 2 edges in parallel ----------------
__global__ void agg_x_kernel(const float* __restrict__ x, const float* __restrict__ dinv,
                             const int* __restrict__ rowptr, const int* __restrict__ csr_src,
                             const float* __restrict__ csr_norm, float* __restrict__ xagg) {
  int tid = threadIdx.x;
  int wv = tid >> 6, lane = tid & 63;
  int sub = lane >> 5, q = lane & 31;   // 2 edge slots x 32 float4-chunks
  int n = blockIdx.x * 4 + wv;
  float di = dinv[n];
  const float4* X4 = (const float4*)x;
  float4 a0 = {0,0,0,0}, a1 = {0,0,0,0};
  int e0 = rowptr[n], e1 = rowptr[n + 1];
  int e = e0 + sub;
  for (; e + 2 < e1; e += 4) {
    int s0 = csr_src[e];     float w0 = csr_norm[e];
    int s1 = csr_src[e + 2]; float w1 = csr_norm[e + 2];
    float4 r0 = X4[(size_t)s0 * 32 + q];
    float4 r1 = X4[(size_t)s1 * 32 + q];
    a0.x += w0 * r0.x; a0.y += w0 * r0.y; a0.z += w0 * r0.z; a0.w += w0 * r0.w;
    a1.x += w1 * r1.x; a1.y += w1 * r1.y; a1.z += w1 * r1.z; a1.w += w1 * r1.w;
  }
  for (; e < e1; e += 2) {
    int s0 = csr_src[e]; float w0 = csr_norm[e];
    float4 r0 = X4[(size_t)s0 * 32 + q];
    a0.x += w0 * r0.x; a0.y += w0 * r0.y; a0.z += w0 * r0.z; a0.w += w0 * r0.w;
  }
  a0.x += a1.x; a0.y += a1.y; a0.z += a1.z; a0.w += a1.w;
  a0.x += __shfl_xor(a0.x, 32, 64);
  a0.y += __shfl_xor(a0.y, 32, 64);
  a0.z += __shfl_xor(a0.z, 32, 64);
  a0.w += __shfl_xor(a0.w, 32, 64);
  float4 own = X4[(size_t)n * 32 + q];
  float dd = di * di;
  if (sub == 0) {
    float4 r;
    r.x = a0.x + dd * own.x; r.y = a0.y + dd * own.y;
    r.z = a0.z + dd * own.z; r.w = a0.w + dd * own.w;
    ((float4*)xagg)[(size_t)n * 32 + q] = r;
  }
}

// ================= NARROW PATH (per-t, proven footprint) =================
__global__ void layer1N_kernel(const float* __restrict__ xagg, const float* __restrict__ W1,
                               const float* __restrict__ b1, const float* __restrict__ W2,
                               float* __restrict__ GA, int t) {
  __shared__ float hs[4][H];
  int tid = threadIdx.x;
  int wv = tid >> 6, j = tid & 63;
  int n = blockIdx.x * 4 + wv;
  const float* xa = xagg + (size_t)n * 128;
  float a = b1[j];
  #pragma unroll
  for (int f = 0; f < 16; ++f) a += xa[f * 8 + t] * W1[f * H + j];
  hs[wv][j] = fmaxf(a, 0.f);
  __syncthreads();
  float g = 0.f;
  #pragma unroll
  for (int k = 0; k < H; ++k) g += hs[wv][k] * W2[k * H + j];
  GA[(size_t)n * H + j] = g;
}

template<bool ACCUM>
__global__ void convN_kernel(const float* __restrict__ Gin, const float* __restrict__ dinv,
                             const int* __restrict__ rowptr, const int* __restrict__ csr_src,
                             const float* __restrict__ csr_norm, const float* __restrict__ b,
                             const float* __restrict__ Wnext, float* __restrict__ Gout) {
  __shared__ __align__(16) float hs[4][H];
  int tid = threadIdx.x;
  int wv = tid >> 6, lane = tid & 63;
  int sub = lane >> 4, q = lane & 15;   // 4 edge slots x 16 float4-chunks
  int n = blockIdx.x * 4 + wv;
  float di = dinv[n];
  const float4* G4 = (const float4*)Gin;
  float4 a0 = {0,0,0,0}, a1 = {0,0,0,0};
  int e0 = rowptr[n], e1 = rowptr[n + 1];
  int e = e0 + sub;
  for (; e + 4 < e1; e += 8) {
    int s0 = csr_src[e];     float w0 = csr_norm[e];
    int s1 = csr_src[e + 4]; float w1 = csr_norm[e + 4];
    float4 r0 = G4[(size_t)s0 * 16 + q];
    float4 r1 = G4[(size_t)s1 * 16 + q];
    a0.x += w0 * r0.x; a0.y += w0 * r0.y; a0.z += w0 * r0.z; a0.w += w0 * r0.w;
    a1.x += w1 * r1.x; a1.y += w1 * r1.y; a1.z += w1 * r1.z; a1.w += w1 * r1.w;
  }
  for (; e < e1; e += 4) {
    int s0 = csr_src[e]; float w0 = csr_norm[e];
    float4 r0 = G4[(size_t)s0 * 16 + q];
    a0.x += w0 * r0.x; a0.y += w0 * r0.y; a0.z += w0 * r0.z; a0.w += w0 * r0.w;
  }
  a0.x += a1.x; a0.y += a1.y; a0.z += a1.z; a0.w += a1.w;
  #pragma unroll
  for (int off = 16; off <= 32; off <<= 1) {
    a0.x += __shfl_xor(a0.x, off, 64);
    a0.y += __shfl_xor(a0.y, off, 64);
    a0.z += __shfl_xor(a0.z, off, 64);
    a0.w += __shfl_xor(a0.w, off, 64);
  }
  float4 own = G4[(size_t)n * 16 + q];
  float dd = di * di;
  if (sub == 0) {
    float4 h;
    h.x = fmaxf(a0.x + dd * own.x + b[4 * q + 0], 0.f);
    h.y = fmaxf(a0.y + dd * own.y + b[4 * q + 1], 0.f);
    h.z = fmaxf(a0.z + dd * own.z + b[4 * q + 2], 0.f);
    h.w = fmaxf(a0.w + dd * own.w + b[4 * q + 3], 0.f);
    ((float4*)hs[wv])[q] = h;
  }
  __syncthreads();
  float g = 0.f;
  #pragma unroll
  for (int k = 0; k < H; ++k) g += hs[wv][k] * Wnext[k * H + lane];
  if (ACCUM) Gout[(size_t)n * H + lane] += g;
  else       Gout[(size_t)n * H + lane]  = g;
}

// ================= WIDE PATH (4 timesteps per pass, 256-ch rows) =================
// layer1 + layer2-dense fused, 16 nodes per block
__global__ void dense12_kernel(const float* __restrict__ xagg, const float* __restrict__ W1,
                               const float* __restrict__ b1, const float* __restrict__ W2,
                               float* __restrict__ G2, int t0) {
  __shared__ float xs[128];
  __shared__ float hs[256];
  int c = threadIdx.x;
  int tl = c >> 6, j = c & 63;
  int t = t0 + tl;
  for (int nb = 0; nb < 16; ++nb) {
    int n = blockIdx.x * 16 + nb;
    __syncthreads();
    if (c < 128) xs[c] = xagg[(size_t)n * 128 + c];
    __syncthreads();
    float a = b1[j];
    #pragma unroll
    for (int f = 0; f < 16; ++f) a += xs[f * 8 + t] * W1[f * 64 + j];
    hs[c] = fmaxf(a, 0.f);
    __syncthreads();
    float g = 0.f;
    #pragma unroll
    for (int k = 0; k < 64; ++k) g += hs[tl * 64 + k] * W2[k * 64 + j];
    G2[(size_t)n * 256 + c] = g;
  }
}

// gather 256-ch rows; h2 = relu(agg+b2); G3 = h2 @ W3 per t
__global__ void conv2w_kernel(const float* __restrict__ Gin, const float* __restrict__ dinv,
                              const int* __restrict__ rowptr, const int* __restrict__ csr_src,
                              const float* __restrict__ csr_norm, const float* __restrict__ b2,
                              const float* __restrict__ W3, float* __restrict__ Gout) {
  __shared__ float hs[256];
  int c2 = threadIdx.x;  // 0..127, channels 2c2,2c2+1
  int n = blockIdx.x;
  float di = dinv[n];
  const float2* Gv = (const float2*)Gin;
  float2 a0 = {0,0}, a1 = {0,0}, a2 = {0,0}, a3 = {0,0};
  int e0 = rowptr[n], e1 = rowptr[n + 1];
  int e = e0;
  for (; e + 4 <= e1; e += 4) {
    int s0 = csr_src[e],     s1 = csr_src[e + 1];
    int s2 = csr_src[e + 2], s3 = csr_src[e + 3];
    float w0 = csr_norm[e],     w1 = csr_norm[e + 1];
    float w2 = csr_norm[e + 2], w3 = csr_norm[e + 3];
    float2 r0 = Gv[(size_t)s0 * 128 + c2];
    float2 r1 = Gv[(size_t)s1 * 128 + c2];
    float2 r2 = Gv[(size_t)s2 * 128 + c2];
    float2 r3 = Gv[(size_t)s3 * 128 + c2];
    a0.x += w0 * r0.x; a0.y += w0 * r0.y;
    a1.x += w1 * r1.x; a1.y += w1 * r1.y;
    a2.x += w2 * r2.x; a2.y += w2 * r2.y;
    a3.x += w3 * r3.x; a3.y += w3 * r3.y;
  }
  for (; e < e1; ++e) {
    int s0 = csr_src[e]; float w0 = csr_norm[e];
    float2 r0 = Gv[(size_t)s0 * 128 + c2];
    a0.x += w0 * r0.x; a0.y += w0 * r0.y;
  }
  float2 own = Gv[(size_t)n * 128 + c2];
  float dd = di * di;
  int j0 = (2 * c2) & 63;
  float sx = a0.x + a1.x + a2.x + a3.x + dd * own.x + b2[j0];
  float sy = a0.y + a1.y + a2.y + a3.y + dd * own.y + b2[j0 + 1];
  hs[2 * c2]     = fmaxf(sx, 0.f);
  hs[2 * c2 + 1] = fmaxf(sy, 0.f);
  __syncthreads();
  int tl = c2 >> 5;
  int kk = c2 & 31;
  const float2* W3v = (const float2*)W3;
  float gx = 0.f, gy = 0.f;
  #pragma unroll
  for (int k = 0; k < 64; ++k) {
    float2 wv = W3v[k * 32 + kk];
    float h = hs[tl * 64 + k];
    gx += h * wv.x; gy += h * wv.y;
  }
  float2 o; o.x = gx; o.y = gy;
  ((float2*)Gout)[(size_t)n * 128 + c2] = o;
}

// gather 256-ch rows; h3 = relu(agg+b3); acc[n,:64] (+)= sum_t h3_t @ Wseq_t ; 2 nodes/block
__global__ void conv3w_kernel(const float* __restrict__ Gin, const float* __restrict__ dinv,
                              const int* __restrict__ rowptr, const int* __restrict__ csr_src,
                              const float* __restrict__ csr_norm, const float* __restrict__ b3,
                              const float* __restrict__ Wseq_g, float* __restrict__ acc,
                              int accumulate) {
  __shared__ float hs[2][256];
  __shared__ float red[2][2][64];
  int c2 = threadIdx.x;  // 0..127
  int j0 = (2 * c2) & 63;
  const float2* Gv = (const float2*)Gin;
  for (int nb = 0; nb < 2; ++nb) {
    int n = blockIdx.x * 2 + nb;
    float di = dinv[n];
    float2 a0 = {0,0}, a1 = {0,0}, a2 = {0,0}, a3 = {0,0};
    int e0 = rowptr[n], e1 = rowptr[n + 1];
    int e = e0;
    for (; e + 4 <= e1; e += 4) {
      int s0 = csr_src[e],     s1 = csr_src[e + 1];
      int s2 = csr_src[e + 2], s3 = csr_src[e + 3];
      float w0 = csr_norm[e],     w1 = csr_norm[e + 1];
      float w2 = csr_norm[e + 2], w3 = csr_norm[e + 3];
      float2 r0 = Gv[(size_t)s0 * 128 + c2];
      float2 r1 = Gv[(size_t)s1 * 128 + c2];
      float2 r2 = Gv[(size_t)s2 * 128 + c2];
      float2 r3 = Gv[(size_t)s3 * 128 + c2];
      a0.x += w0 * r0.x; a0.y += w0 * r0.y;
      a1.x += w1 * r1.x; a1.y += w1 * r1.y;
      a2.x += w2 * r2.x; a2.y += w2 * r2.y;
      a3.x += w3 * r3.x; a3.y += w3 * r3.y;
    }
    for (; e < e1; ++e) {
      int s0 = csr_src[e]; float w0 = csr_norm[e];
      float2 r0 = Gv[(size_t)s0 * 128 + c2];
      a0.x += w0 * r0.x; a0.y += w0 * r0.y;
    }
    float2 own = Gv[(size_t)n * 128 + c2];
    float dd = di * di;
    float sx = a0.x + a1.x + a2.x + a3.x + dd * own.x + b3[j0];
    float sy = a0.y + a1.y + a2.y + a3.y + dd * own.y + b3[j0 + 1];
    hs[nb][2 * c2]     = fmaxf(sx, 0.f);
    hs[nb][2 * c2 + 1] = fmaxf(sy, 0.f);
  }
  __syncthreads();
  int k = c2 & 63, qq = c2 >> 6;
  float p0 = 0.f, p1 = 0.f;
  #pragma unroll 8
  for (int ci = 0; ci < 128; ++ci) {
    int cch = qq * 128 + ci;
    float wv = Wseq_g[(size_t)cch * 64 + k];
    p0 += hs[0][cch] * wv;
    p1 += hs[1][cch] * wv;
  }
  red[0][qq][k] = p0;
  red[1][qq][k] = p1;
  __syncthreads();
  int nb2 = c2 >> 6, k2 = c2 & 63;
  float v = red[nb2][0][k2] + red[nb2][1][k2];
  size_t idx = (size_t)(blockIdx.x * 2 + nb2) * 64 + k2;
  if (accumulate) acc[idx] += v;
  else            acc[idx]  = v;
}

// ---------------- head: out = relu(acc + bseq) @ Wcls + bcls ----------------
__global__ void final_kernel(const float* __restrict__ acc, const float* __restrict__ bseq,
                             const float* __restrict__ Wcls, const float* __restrict__ bcls,
                             float* __restrict__ out) {
  __shared__ float hs[4][H];
  int tid = threadIdx.x;
  int wv = tid >> 6, j = tid & 63;
  int n = blockIdx.x * 4 + wv;
  hs[wv][j] = fmaxf(acc[(size_t)n * H + j] + bseq[j], 0.0f);
  __syncthreads();
  if (j < C) {
    float o = bcls[j];
    #pragma unroll
    for (int k = 0; k < H; ++k) o += hs[wv][k] * Wcls[k * C + j];
    out[(size_t)n * C + j] = o;
  }
}

extern "C" void kernel_launch(void* const* d_in, const int* in_sizes, int n_in,
                              void* d_out, int out_size, void* d_ws, size_t ws_size,
                              hipStream_t stream) {
  const float* x    = (const float*)d_in[0];
  const int*   ei   = (const int*)  d_in[1];
  const float* w    = (const float*)d_in[2];
  const float* W1   = (const float*)d_in[3];
  const float* b1   = (const float*)d_in[4];
  const float* W2   = (const float*)d_in[5];
  const float* b2   = (const float*)d_in[6];
  const float* W3   = (const float*)d_in[7];
  const float* b3   = (const float*)d_in[8];
  const float* Wseq = (const float*)d_in[9];
  const float* bseq = (const float*)d_in[10];
  const float* Wcls = (const float*)d_in[11];
  const float* bcls = (const float*)d_in[12];
  float* out = (float*)d_out;

  char* p = (char*)d_ws;
  auto alloc = [&](size_t bytes) -> char* {
    char* r = p; p += (bytes + 255) & ~(size_t)255; return r;
  };
  float* deg     = (float*)alloc((size_t)N * 4);        // becomes dinv
  int*   counts  = (int*)  alloc((size_t)N * 4);
  int*   fillc   = (int*)  alloc((size_t)N * 4);
  int*   rowptr  = (int*)  alloc((size_t)(N + 1) * 4);
  int*   csr_src = (int*)  alloc((size_t)E * 4);
  float* csr_nrm = (float*)alloc((size_t)E * 4);
  float* xagg    = (float*)alloc((size_t)N * 128 * 4);

  // common setup
  hipMemsetAsync(deg,    0, (size_t)N * 4, stream);
  hipMemsetAsync(counts, 0, (size_t)N * 4, stream);
  hipMemsetAsync(fillc,  0, (size_t)N * 4, stream);
  deg_count_kernel<<<(E + 255) / 256, 256, 0, stream>>>(ei, w, deg, counts);
  dinv_kernel<<<(N + 255) / 256, 256, 0, stream>>>(deg);
  scan_kernel<<<1, 1024, 0, stream>>>(counts, rowptr);
  fill_kernel<<<(E + 255) / 256, 256, 0, stream>>>(ei, w, deg, rowptr, fillc, csr_src, csr_nrm);
  agg_x_kernel<<<N / 4, 256, 0, stream>>>(x, deg, rowptr, csr_src, csr_nrm, xagg);

  // wide path needs: common (~39.3 MB) + G2 + G3 (51.2 MB each) + acc (12.8 MB)
  bool wide = ws_size >= (size_t)156 * 1000 * 1000;

  if (wide) {
    float* G2  = (float*)alloc((size_t)N * 256 * 4);
    float* G3  = (float*)alloc((size_t)N * 256 * 4);
    float* acc = (float*)alloc((size_t)N * H * 4);
    for (int g = 0; g < 2; ++g) {
      dense12_kernel<<<N / 16, 256, 0, stream>>>(xagg, W1, b1, W2, G2, 4 * g);
      conv2w_kernel<<<N, 128, 0, stream>>>(G2, deg, rowptr, csr_src, csr_nrm, b2, W3, G3);
      conv3w_kernel<<<N / 2, 128, 0, stream>>>(G3, deg, rowptr, csr_src, csr_nrm, b3,
                                               Wseq + (size_t)g * 256 * 64, acc, g);
    }
    final_kernel<<<N / 4, 256, 0, stream>>>(acc, bseq, Wcls, bcls, out);
  } else {
    float* GA  = (float*)alloc((size_t)N * H * 4);
    float* GB  = (float*)alloc((size_t)N * H * 4);
    float* acc = (float*)alloc((size_t)N * H * 4);
    hipMemsetAsync(acc, 0, (size_t)N * H * 4, stream);
    for (int t = 0; t < T; ++t) {
      layer1N_kernel<<<N / 4, 256, 0, stream>>>(xagg, W1, b1, W2, GA, t);
      convN_kernel<false><<<N / 4, 256, 0, stream>>>(GA, deg, rowptr, csr_src, csr_nrm, b2, W3, GB);
      convN_kernel<true ><<<N / 4, 256, 0, stream>>>(GB, deg, rowptr, csr_src, csr_nrm, b3,
                                                     Wseq + (size_t)t * H * H, acc);
    }
    final_kernel<<<N / 4, 256, 0, stream>>>(acc, bseq, Wcls, bcls, out);
  }
}

// Round 3
// 978.948 us; speedup vs baseline: 3.4145x; 1.5664x over previous
//
#include <hip/hip_runtime.h>
#include <hip/hip_fp16.h>

constexpr int N  = 50000;
constexpr int E  = 1600000;
constexpr int T  = 8;
constexpr int H  = 64;
constexpr int C  = 10;

// ---------------- degree + histogram ----------------
__global__ void deg_count_kernel(const int* __restrict__ ei, const float* __restrict__ w,
                                 float* __restrict__ deg, int* __restrict__ counts) {
  int e = blockIdx.x * blockDim.x + threadIdx.x;
  if (e >= E) return;
  int d = ei[E + e];
  atomicAdd(&deg[d], w[e]);
  atomicAdd(&counts[d], 1);
}

__global__ void dinv_kernel(float* deg) {
  int n = blockIdx.x * blockDim.x + threadIdx.x;
  if (n >= N) return;
  deg[n] = rsqrtf(deg[n] + 1.0f);  // +1 = self-loop weight
}

// ---------------- exclusive scan (single block, 1024 threads) ----------------
__global__ void scan_kernel(const int* __restrict__ counts, int* __restrict__ rowptr) {
  __shared__ int wsum[16];
  __shared__ int carry_s;
  int tid = threadIdx.x;
  if (tid == 0) carry_s = 0;
  __syncthreads();
  for (int base = 0; base < N; base += 1024) {
    int i = base + tid;
    int v = (i < N) ? counts[i] : 0;
    int x = v;
    #pragma unroll
    for (int off = 1; off < 64; off <<= 1) {
      int y = __shfl_up(x, off, 64);
      if ((tid & 63) >= off) x += y;
    }
    if ((tid & 63) == 63) wsum[tid >> 6] = x;
    __syncthreads();
    if (tid < 16) {
      int wv = wsum[tid];
      #pragma unroll
      for (int off = 1; off < 16; off <<= 1) {
        int y = __shfl_up(wv, off, 16);
        if (tid >= off) wv += y;
      }
      wsum[tid] = wv;
    }
    __syncthreads();
    int carry = carry_s;
    int waveoff = (tid >> 6) ? wsum[(tid >> 6) - 1] : 0;
    int inc = x + waveoff + carry;
    if (i < N) rowptr[i + 1] = inc;
    __syncthreads();
    if (tid == 1023) carry_s = inc;
    __syncthreads();
  }
  if (tid == 0) rowptr[0] = 0;
}

// ---------------- CSR fill ----------------
__global__ void fill_kernel(const int* __restrict__ ei, const float* __restrict__ w,
                            const float* __restrict__ dinv, const int* __restrict__ rowptr,
                            int* __restrict__ fill, int* __restrict__ csr_src,
                            float* __restrict__ csr_norm) {
  int e = blockIdx.x * blockDim.x + threadIdx.x;
  if (e >= E) return;
  int s = ei[e], d = ei[E + e];
  int pos = rowptr[d] + atomicAdd(&fill[d], 1);
  csr_src[pos] = s;
  csr_norm[pos] = dinv[s] * w[e] * dinv[d];
}

// ---------------- x (fp32) -> xh (fp16) ----------------
__global__ void cvt_x_kernel(const float* __restrict__ x, __half* __restrict__ xh) {
  int i = blockIdx.x * blockDim.x + threadIdx.x;  // over N*32 float4s
  if (i >= N * 32) return;
  float4 v = ((const float4*)x)[i];
  __half2 h0; h0.x = __float2half_rn(v.x); h0.y = __float2half_rn(v.y);
  __half2 h1; h1.x = __float2half_rn(v.z); h1.y = __float2half_rn(v.w);
  uint2 u;
  u.x = __builtin_bit_cast(unsigned int, h0);
  u.y = __builtin_bit_cast(unsigned int, h1);
  ((uint2*)xh)[i] = u;
}

// ---------------- xagg = Ahat @ X, fp16 rows (256B), wave/node ----------------
__global__ void agg_x_kernel(const __half* __restrict__ xh, const float* __restrict__ dinv,
                             const int* __restrict__ rowptr, const int* __restrict__ csr_src,
                             const float* __restrict__ csr_norm, float* __restrict__ xagg) {
  int tid = threadIdx.x;
  int w = tid >> 6, l = tid & 63;
  int sub = l >> 5, c4 = l & 31;     // half-wave: 2 items x 32 lanes x 4ch
  int n = blockIdx.x * 4 + w;
  float di = dinv[n], dd = di * di;
  int e0 = rowptr[n], e1 = rowptr[n + 1];
  int cnt = e1 - e0 + 1;             // item 0 = self
  float4 acc = {0, 0, 0, 0};
  int i = sub;
  int sA = 0; float wA = 0.f;
  if (i < cnt) {
    if (i == 0) { sA = n; wA = dd; }
    else { int e = e0 + i - 1; sA = csr_src[e]; wA = csr_norm[e]; }
  }
  while (i < cnt) {
    uint2 r = *reinterpret_cast<const uint2*>(xh + (size_t)sA * 128 + c4 * 4);
    int ni = i + 2;
    int sB = 0; float wB = 0.f;
    if (ni < cnt) { int e = e0 + ni - 1; sB = csr_src[e]; wB = csr_norm[e]; }
    float2 f0 = __half22float2(__builtin_bit_cast(__half2, r.x));
    float2 f1 = __half22float2(__builtin_bit_cast(__half2, r.y));
    acc.x = fmaf(wA, f0.x, acc.x);
    acc.y = fmaf(wA, f0.y, acc.y);
    acc.z = fmaf(wA, f1.x, acc.z);
    acc.w = fmaf(wA, f1.y, acc.w);
    sA = sB; wA = wB; i = ni;
  }
  acc.x += __shfl_xor(acc.x, 32, 64);
  acc.y += __shfl_xor(acc.y, 32, 64);
  acc.z += __shfl_xor(acc.z, 32, 64);
  acc.w += __shfl_xor(acc.w, 32, 64);
  if (sub == 0) ((float4*)(xagg + (size_t)n * 128))[c4] = acc;
}

// ---------------- dense: h1 = relu(xagg_t @ W1 + b1); G2 = h1 @ W2 (fp16, all t) ----------------
__global__ void dense12_kernel(const float* __restrict__ xagg, const float* __restrict__ W1,
                               const float* __restrict__ b1, const float* __restrict__ W2,
                               __half* __restrict__ G2h) {
  __shared__ float xs[4 * 128];
  __shared__ float h1s[4][8][64];
  int tid = threadIdx.x;
  int n0 = blockIdx.x * 4;
  ((float2*)xs)[tid] = ((const float2*)(xagg + (size_t)n0 * 128))[tid];
  __syncthreads();
  int nb = tid >> 6, j = tid & 63;
  float a[8];
  float bj = b1[j];
  #pragma unroll
  for (int t = 0; t < 8; ++t) a[t] = bj;
  for (int f = 0; f < 16; ++f) {
    float wv = W1[f * 64 + j];
    #pragma unroll
    for (int t = 0; t < 8; ++t) a[t] = fmaf(xs[nb * 128 + f * 8 + t], wv, a[t]);
  }
  #pragma unroll
  for (int t = 0; t < 8; ++t) h1s[nb][t][j] = fmaxf(a[t], 0.f);
  __syncthreads();
  float g[8];
  #pragma unroll
  for (int t = 0; t < 8; ++t) g[t] = 0.f;
  for (int k = 0; k < 64; ++k) {
    float wv = W2[k * 64 + j];
    #pragma unroll
    for (int t = 0; t < 8; ++t) g[t] = fmaf(h1s[nb][t][k], wv, g[t]);
  }
  __half* gp = G2h + (size_t)(n0 + nb) * 512 + j;
  #pragma unroll
  for (int t = 0; t < 8; ++t) gp[t * 64] = __float2half_rn(g[t]);
}

// ---------------- conv2: aggregate G2h (1KB fp16 rows); h2=relu(+b2); G3h = h2 @ W3 ----------------
__global__ void conv2w_kernel(const __half* __restrict__ G2h, const float* __restrict__ dinv,
                              const int* __restrict__ rowptr, const int* __restrict__ csr_src,
                              const float* __restrict__ csr_norm, const float* __restrict__ b2,
                              const float* __restrict__ W3, __half* __restrict__ G3h) {
  __shared__ float h2s[4][512];
  int tid = threadIdx.x;
  int w = tid >> 6, l = tid & 63;
  int n0 = blockIdx.x * 4;
  int n = n0 + w;
  float di = dinv[n], dd = di * di;
  int e0 = rowptr[n], e1 = rowptr[n + 1];
  int cnt = e1 - e0 + 1;
  float acc[8] = {0, 0, 0, 0, 0, 0, 0, 0};
  int i = 0;
  int sA = n; float wA = dd;  // item 0 = self
  while (i < cnt) {
    bool has2 = (i + 1) < cnt;
    int sB = 0; float wB = 0.f;
    if (has2) { int e = e0 + i; sB = csr_src[e]; wB = csr_norm[e]; }
    uint4 rA = *reinterpret_cast<const uint4*>(G2h + (size_t)sA * 512 + l * 8);
    uint4 rB = {0, 0, 0, 0};
    if (has2) rB = *reinterpret_cast<const uint4*>(G2h + (size_t)sB * 512 + l * 8);
    {
      float2 f0 = __half22float2(__builtin_bit_cast(__half2, rA.x));
      float2 f1 = __half22float2(__builtin_bit_cast(__half2, rA.y));
      float2 f2 = __half22float2(__builtin_bit_cast(__half2, rA.z));
      float2 f3 = __half22float2(__builtin_bit_cast(__half2, rA.w));
      acc[0] = fmaf(wA, f0.x, acc[0]); acc[1] = fmaf(wA, f0.y, acc[1]);
      acc[2] = fmaf(wA, f1.x, acc[2]); acc[3] = fmaf(wA, f1.y, acc[3]);
      acc[4] = fmaf(wA, f2.x, acc[4]); acc[5] = fmaf(wA, f2.y, acc[5]);
      acc[6] = fmaf(wA, f3.x, acc[6]); acc[7] = fmaf(wA, f3.y, acc[7]);
    }
    if (has2) {
      float2 f0 = __half22float2(__builtin_bit_cast(__half2, rB.x));
      float2 f1 = __half22float2(__builtin_bit_cast(__half2, rB.y));
      float2 f2 = __half22float2(__builtin_bit_cast(__half2, rB.z));
      float2 f3 = __half22float2(__builtin_bit_cast(__half2, rB.w));
      acc[0] = fmaf(wB, f0.x, acc[0]); acc[1] = fmaf(wB, f0.y, acc[1]);
      acc[2] = fmaf(wB, f1.x, acc[2]); acc[3] = fmaf(wB, f1.y, acc[3]);
      acc[4] = fmaf(wB, f2.x, acc[4]); acc[5] = fmaf(wB, f2.y, acc[5]);
      acc[6] = fmaf(wB, f3.x, acc[6]); acc[7] = fmaf(wB, f3.y, acc[7]);
    }
    i += 2;
    if (i < cnt) { int e = e0 + i - 1; sA = csr_src[e]; wA = csr_norm[e]; }
  }
  #pragma unroll
  for (int q = 0; q < 8; ++q)
    h2s[w][l * 8 + q] = fmaxf(acc[q] + b2[(l * 8 + q) & 63], 0.f);
  __syncthreads();
  // per-t dense: G3[t*64 + j] = sum_k h2[t*64+k] * W3[k][j]
  int t = tid >> 5;            // 0..7
  int jh = tid & 31, j0 = 2 * jh;
  float g[4][2];
  #pragma unroll
  for (int q = 0; q < 4; ++q) { g[q][0] = 0.f; g[q][1] = 0.f; }
  const float2* W3v = (const float2*)W3;
  for (int k = 0; k < 64; ++k) {
    float2 wv = W3v[k * 32 + jh];
    #pragma unroll
    for (int q = 0; q < 4; ++q) {
      float h = h2s[q][t * 64 + k];
      g[q][0] = fmaf(h, wv.x, g[q][0]);
      g[q][1] = fmaf(h, wv.y, g[q][1]);
    }
  }
  #pragma unroll
  for (int q = 0; q < 4; ++q) {
    __half2 hv;
    hv.x = __float2half_rn(g[q][0]);
    hv.y = __float2half_rn(g[q][1]);
    *reinterpret_cast<__half2*>(G3h + (size_t)(n0 + q) * 512 + t * 64 + j0) = hv;
  }
}

// ---------------- conv3 + head: aggregate G3h; h3=relu(+b3); out = relu(h3@Wseq+bseq)@Wcls+bcls ----------------
__global__ void conv3w_kernel(const __half* __restrict__ G3h, const float* __restrict__ dinv,
                              const int* __restrict__ rowptr, const int* __restrict__ csr_src,
                              const float* __restrict__ csr_norm, const float* __restrict__ b3,
                              const float* __restrict__ Wseq, const float* __restrict__ bseq,
                              const float* __restrict__ Wcls, const float* __restrict__ bcls,
                              float* __restrict__ out) {
  __shared__ float h3s[4][512];
  __shared__ float red[4][4][64];
  __shared__ float hfs[4][64];
  int tid = threadIdx.x;
  int w = tid >> 6, l = tid & 63;
  int n0 = blockIdx.x * 4;
  int n = n0 + w;
  float di = dinv[n], dd = di * di;
  int e0 = rowptr[n], e1 = rowptr[n + 1];
  int cnt = e1 - e0 + 1;
  float acc[8] = {0, 0, 0, 0, 0, 0, 0, 0};
  int i = 0;
  int sA = n; float wA = dd;
  while (i < cnt) {
    bool has2 = (i + 1) < cnt;
    int sB = 0; float wB = 0.f;
    if (has2) { int e = e0 + i; sB = csr_src[e]; wB = csr_norm[e]; }
    uint4 rA = *reinterpret_cast<const uint4*>(G3h + (size_t)sA * 512 + l * 8);
    uint4 rB = {0, 0, 0, 0};
    if (has2) rB = *reinterpret_cast<const uint4*>(G3h + (size_t)sB * 512 + l * 8);
    {
      float2 f0 = __half22float2(__builtin_bit_cast(__half2, rA.x));
      float2 f1 = __half22float2(__builtin_bit_cast(__half2, rA.y));
      float2 f2 = __half22float2(__builtin_bit_cast(__half2, rA.z));
      float2 f3 = __half22float2(__builtin_bit_cast(__half2, rA.w));
      acc[0] = fmaf(wA, f0.x, acc[0]); acc[1] = fmaf(wA, f0.y, acc[1]);
      acc[2] = fmaf(wA, f1.x, acc[2]); acc[3] = fmaf(wA, f1.y, acc[3]);
      acc[4] = fmaf(wA, f2.x, acc[4]); acc[5] = fmaf(wA, f2.y, acc[5]);
      acc[6] = fmaf(wA, f3.x, acc[6]); acc[7] = fmaf(wA, f3.y, acc[7]);
    }
    if (has2) {
      float2 f0 = __half22float2(__builtin_bit_cast(__half2, rB.x));
      float2 f1 = __half22float2(__builtin_bit_cast(__half2, rB.y));
      float2 f2 = __half22float2(__builtin_bit_cast(__half2, rB.z));
      float2 f3 = __half22float2(__builtin_bit_cast(__half2, rB.w));
      acc[0] = fmaf(wB, f0.x, acc[0]); acc[1] = fmaf(wB, f0.y, acc[1]);
      acc[2] = fmaf(wB, f1.x, acc[2]); acc[3] = fmaf(wB, f1.y, acc[3]);
      acc[4] = fmaf(wB, f2.x, acc[4]); acc[5] = fmaf(wB, f2.y, acc[5]);
      acc[6] = fmaf(wB, f3.x, acc[6]); acc[7] = fmaf(wB, f3.y, acc[7]);
    }
    i += 2;
    if (i < cnt) { int e = e0 + i - 1; sA = csr_src[e]; wA = csr_norm[e]; }
  }
  #pragma unroll
  for (int q = 0; q < 8; ++q)
    h3s[w][l * 8 + q] = fmaxf(acc[q] + b3[(l * 8 + q) & 63], 0.f);
  __syncthreads();
  // seq contraction: partial[p][nb][j] = sum_{c in p-range} h3[nb][c] * Wseq[c][j]
  int p = tid >> 6, j = tid & 63;
  float pa0 = 0.f, pa1 = 0.f, pa2 = 0.f, pa3 = 0.f;
  for (int ci = 0; ci < 128; ++ci) {
    int c = p * 128 + ci;
    float wv = Wseq[(size_t)c * 64 + j];
    pa0 = fmaf(h3s[0][c], wv, pa0);
    pa1 = fmaf(h3s[1][c], wv, pa1);
    pa2 = fmaf(h3s[2][c], wv, pa2);
    pa3 = fmaf(h3s[3][c], wv, pa3);
  }
  red[p][0][j] = pa0; red[p][1][j] = pa1; red[p][2][j] = pa2; red[p][3][j] = pa3;
  __syncthreads();
  int nb = tid >> 6, k = tid & 63;
  float s = red[0][nb][k] + red[1][nb][k] + red[2][nb][k] + red[3][nb][k] + bseq[k];
  hfs[nb][k] = fmaxf(s, 0.f);
  __syncthreads();
  if (k < C) {
    float o = bcls[k];
    #pragma unroll
    for (int kk = 0; kk < 64; ++kk) o = fmaf(hfs[nb][kk], Wcls[kk * C + k], o);
    out[(size_t)(n0 + nb) * C + k] = o;
  }
}

// ================= NARROW FALLBACK (fp32, per-t) =================
__global__ void layer1N_kernel(const float* __restrict__ xagg, const float* __restrict__ W1,
                               const float* __restrict__ b1, const float* __restrict__ W2,
                               float* __restrict__ GA, int t) {
  __shared__ float hs[4][H];
  int tid = threadIdx.x;
  int wv = tid >> 6, j = tid & 63;
  int n = blockIdx.x * 4 + wv;
  const float* xa = xagg + (size_t)n * 128;
  float a = b1[j];
  #pragma unroll
  for (int f = 0; f < 16; ++f) a += xa[f * 8 + t] * W1[f * H + j];
  hs[wv][j] = fmaxf(a, 0.f);
  __syncthreads();
  float g = 0.f;
  #pragma unroll
  for (int k = 0; k < H; ++k) g += hs[wv][k] * W2[k * H + j];
  GA[(size_t)n * H + j] = g;
}

template<bool ACCUM>
__global__ void convN_kernel(const float* __restrict__ Gin, const float* __restrict__ dinv,
                             const int* __restrict__ rowptr, const int* __restrict__ csr_src,
                             const float* __restrict__ csr_norm, const float* __restrict__ b,
                             const float* __restrict__ Wnext, float* __restrict__ Gout) {
  __shared__ __align__(16) float hs[4][H];
  int tid = threadIdx.x;
  int wv = tid >> 6, lane = tid & 63;
  int sub = lane >> 4, q = lane & 15;
  int n = blockIdx.x * 4 + wv;
  float di = dinv[n];
  const float4* G4 = (const float4*)Gin;
  float4 a0 = {0,0,0,0}, a1 = {0,0,0,0};
  int e0 = rowptr[n], e1 = rowptr[n + 1];
  int e = e0 + sub;
  for (; e + 4 < e1; e += 8) {
    int s0 = csr_src[e];     float w0 = csr_norm[e];
    int s1 = csr_src[e + 4]; float w1 = csr_norm[e + 4];
    float4 r0 = G4[(size_t)s0 * 16 + q];
    float4 r1 = G4[(size_t)s1 * 16 + q];
    a0.x += w0 * r0.x; a0.y += w0 * r0.y; a0.z += w0 * r0.z; a0.w += w0 * r0.w;
    a1.x += w1 * r1.x; a1.y += w1 * r1.y; a1.z += w1 * r1.z; a1.w += w1 * r1.w;
  }
  for (; e < e1; e += 4) {
    int s0 = csr_src[e]; float w0 = csr_norm[e];
    float4 r0 = G4[(size_t)s0 * 16 + q];
    a0.x += w0 * r0.x; a0.y += w0 * r0.y; a0.z += w0 * r0.z; a0.w += w0 * r0.w;
  }
  a0.x += a1.x; a0.y += a1.y; a0.z += a1.z; a0.w += a1.w;
  #pragma unroll
  for (int off = 16; off <= 32; off <<= 1) {
    a0.x += __shfl_xor(a0.x, off, 64);
    a0.y += __shfl_xor(a0.y, off, 64);
    a0.z += __shfl_xor(a0.z, off, 64);
    a0.w += __shfl_xor(a0.w, off, 64);
  }
  float4 own = G4[(size_t)n * 16 + q];
  float dd = di * di;
  if (sub == 0) {
    float4 h;
    h.x = fmaxf(a0.x + dd * own.x + b[4 * q + 0], 0.f);
    h.y = fmaxf(a0.y + dd * own.y + b[4 * q + 1], 0.f);
    h.z = fmaxf(a0.z + dd * own.z + b[4 * q + 2], 0.f);
    h.w = fmaxf(a0.w + dd * own.w + b[4 * q + 3], 0.f);
    ((float4*)hs[wv])[q] = h;
  }
  __syncthreads();
  float g = 0.f;
  #pragma unroll
  for (int k = 0; k < H; ++k) g += hs[wv][k] * Wnext[k * H + lane];
  if (ACCUM) Gout[(size_t)n * H + lane] += g;
  else       Gout[(size_t)n * H + lane]  = g;
}

__global__ void final_kernel(const float* __restrict__ acc, const float* __restrict__ bseq,
                             const float* __restrict__ Wcls, const float* __restrict__ bcls,
                             float* __restrict__ out) {
  __shared__ float hs[4][H];
  int tid = threadIdx.x;
  int wv = tid >> 6, j = tid & 63;
  int n = blockIdx.x * 4 + wv;
  hs[wv][j] = fmaxf(acc[(size_t)n * H + j] + bseq[j], 0.0f);
  __syncthreads();
  if (j < C) {
    float o = bcls[j];
    #pragma unroll
    for (int k = 0; k < H; ++k) o += hs[wv][k] * Wcls[k * C + j];
    out[(size_t)n * C + j] = o;
  }
}

extern "C" void kernel_launch(void* const* d_in, const int* in_sizes, int n_in,
                              void* d_out, int out_size, void* d_ws, size_t ws_size,
                              hipStream_t stream) {
  const float* x    = (const float*)d_in[0];
  const int*   ei   = (const int*)  d_in[1];
  const float* w    = (const float*)d_in[2];
  const float* W1   = (const float*)d_in[3];
  const float* b1   = (const float*)d_in[4];
  const float* W2   = (const float*)d_in[5];
  const float* b2   = (const float*)d_in[6];
  const float* W3   = (const float*)d_in[7];
  const float* b3   = (const float*)d_in[8];
  const float* Wseq = (const float*)d_in[9];
  const float* bseq = (const float*)d_in[10];
  const float* Wcls = (const float*)d_in[11];
  const float* bcls = (const float*)d_in[12];
  float* out = (float*)d_out;

  char* p = (char*)d_ws;
  auto alloc = [&](size_t bytes) -> char* {
    char* r = p; p += (bytes + 255) & ~(size_t)255; return r;
  };
  float*  deg     = (float*) alloc((size_t)N * 4);      // becomes dinv
  int*    counts  = (int*)   alloc((size_t)N * 4);
  int*    fillc   = (int*)   alloc((size_t)N * 4);
  int*    rowptr  = (int*)   alloc((size_t)(N + 1) * 4);
  int*    csr_src = (int*)   alloc((size_t)E * 4);
  float*  csr_nrm = (float*) alloc((size_t)E * 4);
  float*  xagg    = (float*) alloc((size_t)N * 128 * 4);
  __half* xh      = (__half*)alloc((size_t)N * 128 * 2);

  hipMemsetAsync(deg,    0, (size_t)N * 4, stream);
  hipMemsetAsync(counts, 0, (size_t)N * 4, stream);
  hipMemsetAsync(fillc,  0, (size_t)N * 4, stream);

  cvt_x_kernel<<<(N * 32 + 255) / 256, 256, 0, stream>>>(x, xh);
  deg_count_kernel<<<(E + 255) / 256, 256, 0, stream>>>(ei, w, deg, counts);
  dinv_kernel<<<(N + 255) / 256, 256, 0, stream>>>(deg);
  scan_kernel<<<1, 1024, 0, stream>>>(counts, rowptr);
  fill_kernel<<<(E + 255) / 256, 256, 0, stream>>>(ei, w, deg, rowptr, fillc, csr_src, csr_nrm);
  agg_x_kernel<<<N / 4, 256, 0, stream>>>(xh, deg, rowptr, csr_src, csr_nrm, xagg);

  // wide needs: common 52MB + G2h 51.2MB + G3h 51.2MB ~= 154.6MB
  bool wide = ws_size >= (size_t)155 * 1000 * 1000;

  if (wide) {
    __half* G2h = (__half*)alloc((size_t)N * 512 * 2);
    __half* G3h = (__half*)alloc((size_t)N * 512 * 2);
    dense12_kernel<<<N / 4, 256, 0, stream>>>(xagg, W1, b1, W2, G2h);
    conv2w_kernel<<<N / 4, 256, 0, stream>>>(G2h, deg, rowptr, csr_src, csr_nrm, b2, W3, G3h);
    conv3w_kernel<<<N / 4, 256, 0, stream>>>(G3h, deg, rowptr, csr_src, csr_nrm, b3,
                                             Wseq, bseq, Wcls, bcls, out);
  } else {
    float* GA  = (float*)alloc((size_t)N * H * 4);
    float* GB  = (float*)alloc((size_t)N * H * 4);
    float* acc = (float*)alloc((size_t)N * H * 4);
    hipMemsetAsync(acc, 0, (size_t)N * H * 4, stream);
    for (int t = 0; t < T; ++t) {
      layer1N_kernel<<<N / 4, 256, 0, stream>>>(xagg, W1, b1, W2, GA, t);
      convN_kernel<false><<<N / 4, 256, 0, stream>>>(GA, deg, rowptr, csr_src, csr_nrm, b2, W3, GB);
      convN_kernel<true ><<<N / 4, 256, 0, stream>>>(GB, deg, rowptr, csr_src, csr_nrm, b3,
                                                     Wseq + (size_t)t * H * H, acc);
    }
    final_kernel<<<N / 4, 256, 0, stream>>>(acc, bseq, Wcls, bcls, out);
  }
}

// Round 4
// 878.752 us; speedup vs baseline: 3.8038x; 1.1140x over previous
//
#include <hip/hip_runtime.h>
#include <hip/hip_fp16.h>

constexpr int N  = 50000;
constexpr int E  = 1600000;
constexpr int T  = 8;
constexpr int H  = 64;
constexpr int C  = 10;

// ---------------- degree + histogram ----------------
__global__ void deg_count_kernel(const int* __restrict__ ei, const float* __restrict__ w,
                                 float* __restrict__ deg, int* __restrict__ counts) {
  int e = blockIdx.x * blockDim.x + threadIdx.x;
  if (e >= E) return;
  int d = ei[E + e];
  atomicAdd(&deg[d], w[e]);
  atomicAdd(&counts[d], 1);
}

__global__ void dinv_kernel(float* deg) {
  int n = blockIdx.x * blockDim.x + threadIdx.x;
  if (n >= N) return;
  deg[n] = rsqrtf(deg[n] + 1.0f);  // +1 = self-loop weight
}

// ---------------- exclusive scan (single block, 1024 threads) ----------------
__global__ void scan_kernel(const int* __restrict__ counts, int* __restrict__ rowptr) {
  __shared__ int wsum[16];
  __shared__ int carry_s;
  int tid = threadIdx.x;
  if (tid == 0) carry_s = 0;
  __syncthreads();
  for (int base = 0; base < N; base += 1024) {
    int i = base + tid;
    int v = (i < N) ? counts[i] : 0;
    int x = v;
    #pragma unroll
    for (int off = 1; off < 64; off <<= 1) {
      int y = __shfl_up(x, off, 64);
      if ((tid & 63) >= off) x += y;
    }
    if ((tid & 63) == 63) wsum[tid >> 6] = x;
    __syncthreads();
    if (tid < 16) {
      int wv = wsum[tid];
      #pragma unroll
      for (int off = 1; off < 16; off <<= 1) {
        int y = __shfl_up(wv, off, 16);
        if (tid >= off) wv += y;
      }
      wsum[tid] = wv;
    }
    __syncthreads();
    int carry = carry_s;
    int waveoff = (tid >> 6) ? wsum[(tid >> 6) - 1] : 0;
    int inc = x + waveoff + carry;
    if (i < N) rowptr[i + 1] = inc;
    __syncthreads();
    if (tid == 1023) carry_s = inc;
    __syncthreads();
  }
  if (tid == 0) rowptr[0] = 0;
}

// ---------------- CSR fill ----------------
__global__ void fill_kernel(const int* __restrict__ ei, const float* __restrict__ w,
                            const float* __restrict__ dinv, const int* __restrict__ rowptr,
                            int* __restrict__ fill, int* __restrict__ csr_src,
                            float* __restrict__ csr_norm) {
  int e = blockIdx.x * blockDim.x + threadIdx.x;
  if (e >= E) return;
  int s = ei[e], d = ei[E + e];
  int pos = rowptr[d] + atomicAdd(&fill[d], 1);
  csr_src[pos] = s;
  csr_norm[pos] = dinv[s] * w[e] * dinv[d];
}

// ---------------- x (fp32) -> xh (fp16) ----------------
__global__ void cvt_x_kernel(const float* __restrict__ x, __half* __restrict__ xh) {
  int i = blockIdx.x * blockDim.x + threadIdx.x;  // over N*32 float4s
  if (i >= N * 32) return;
  float4 v = ((const float4*)x)[i];
  __half2 h0; h0.x = __float2half_rn(v.x); h0.y = __float2half_rn(v.y);
  __half2 h1; h1.x = __float2half_rn(v.z); h1.y = __float2half_rn(v.w);
  uint2 u;
  u.x = __builtin_bit_cast(unsigned int, h0);
  u.y = __builtin_bit_cast(unsigned int, h1);
  ((uint2*)xh)[i] = u;
}

// ---------------- xagg = Ahat @ X, fp16 rows (256B), wave/node ----------------
__global__ void agg_x_kernel(const __half* __restrict__ xh, const float* __restrict__ dinv,
                             const int* __restrict__ rowptr, const int* __restrict__ csr_src,
                             const float* __restrict__ csr_norm, float* __restrict__ xagg) {
  int tid = threadIdx.x;
  int w = tid >> 6, l = tid & 63;
  int sub = l >> 5, c4 = l & 31;     // half-wave: 2 items x 32 lanes x 4ch
  int n = blockIdx.x * 4 + w;
  float di = dinv[n], dd = di * di;
  int e0 = rowptr[n], e1 = rowptr[n + 1];
  int cnt = e1 - e0 + 1;             // item 0 = self
  float4 acc = {0, 0, 0, 0};
  // 2 slots per half-wave => 4 rows in flight per wave
  int sm[2]; float wm[2];
  #pragma unroll
  for (int q = 0; q < 2; ++q) {
    int idx = sub + 2 * q;
    if (idx == 0)       { sm[q] = n; wm[q] = dd; }
    else if (idx < cnt) { int e = e0 + idx - 1; sm[q] = csr_src[e]; wm[q] = csr_norm[e]; }
    else                { sm[q] = n; wm[q] = 0.f; }
  }
  for (int i = sub; i < cnt; i += 4) {
    uint2 r0 = *reinterpret_cast<const uint2*>(xh + (size_t)sm[0] * 128 + c4 * 4);
    uint2 r1 = *reinterpret_cast<const uint2*>(xh + (size_t)sm[1] * 128 + c4 * 4);
    float w0 = wm[0], w1 = wm[1];
    #pragma unroll
    for (int q = 0; q < 2; ++q) {
      int idx = i + 4 + 2 * q;
      if (idx < cnt) { int e = e0 + idx - 1; sm[q] = csr_src[e]; wm[q] = csr_norm[e]; }
      else           { sm[q] = n; wm[q] = 0.f; }
    }
    float2 f0 = __half22float2(__builtin_bit_cast(__half2, r0.x));
    float2 f1 = __half22float2(__builtin_bit_cast(__half2, r0.y));
    acc.x = fmaf(w0, f0.x, acc.x); acc.y = fmaf(w0, f0.y, acc.y);
    acc.z = fmaf(w0, f1.x, acc.z); acc.w = fmaf(w0, f1.y, acc.w);
    float2 g0 = __half22float2(__builtin_bit_cast(__half2, r1.x));
    float2 g1 = __half22float2(__builtin_bit_cast(__half2, r1.y));
    acc.x = fmaf(w1, g0.x, acc.x); acc.y = fmaf(w1, g0.y, acc.y);
    acc.z = fmaf(w1, g1.x, acc.z); acc.w = fmaf(w1, g1.y, acc.w);
  }
  acc.x += __shfl_xor(acc.x, 32, 64);
  acc.y += __shfl_xor(acc.y, 32, 64);
  acc.z += __shfl_xor(acc.z, 32, 64);
  acc.w += __shfl_xor(acc.w, 32, 64);
  if (sub == 0) ((float4*)(xagg + (size_t)n * 128))[c4] = acc;
}

// ---------------- dense: h1 = relu(xagg_t @ W1 + b1); G2 = h1 @ W2 (fp16, all t) ----------------
__global__ void dense12_kernel(const float* __restrict__ xagg, const float* __restrict__ W1,
                               const float* __restrict__ b1, const float* __restrict__ W2,
                               __half* __restrict__ G2h) {
  __shared__ float xs[4 * 128];
  __shared__ float h1s[4][8][64];
  int tid = threadIdx.x;
  int n0 = blockIdx.x * 4;
  ((float2*)xs)[tid] = ((const float2*)(xagg + (size_t)n0 * 128))[tid];
  __syncthreads();
  int nb = tid >> 6, j = tid & 63;
  float a[8];
  float bj = b1[j];
  #pragma unroll
  for (int t = 0; t < 8; ++t) a[t] = bj;
  for (int f = 0; f < 16; ++f) {
    float wv = W1[f * 64 + j];
    #pragma unroll
    for (int t = 0; t < 8; ++t) a[t] = fmaf(xs[nb * 128 + f * 8 + t], wv, a[t]);
  }
  #pragma unroll
  for (int t = 0; t < 8; ++t) h1s[nb][t][j] = fmaxf(a[t], 0.f);
  __syncthreads();
  float g[8];
  #pragma unroll
  for (int t = 0; t < 8; ++t) g[t] = 0.f;
  for (int k = 0; k < 64; ++k) {
    float wv = W2[k * 64 + j];
    #pragma unroll
    for (int t = 0; t < 8; ++t) g[t] = fmaf(h1s[nb][t][k], wv, g[t]);
  }
  __half* gp = G2h + (size_t)(n0 + nb) * 512 + j;
  #pragma unroll
  for (int t = 0; t < 8; ++t) gp[t * 64] = __float2half_rn(g[t]);
}

// 8-halves fused accumulate helper
__device__ __forceinline__ void accum8(float* acc, uint4 r, float wgt) {
  float2 f0 = __half22float2(__builtin_bit_cast(__half2, r.x));
  float2 f1 = __half22float2(__builtin_bit_cast(__half2, r.y));
  float2 f2 = __half22float2(__builtin_bit_cast(__half2, r.z));
  float2 f3 = __half22float2(__builtin_bit_cast(__half2, r.w));
  acc[0] = fmaf(wgt, f0.x, acc[0]); acc[1] = fmaf(wgt, f0.y, acc[1]);
  acc[2] = fmaf(wgt, f1.x, acc[2]); acc[3] = fmaf(wgt, f1.y, acc[3]);
  acc[4] = fmaf(wgt, f2.x, acc[4]); acc[5] = fmaf(wgt, f2.y, acc[5]);
  acc[6] = fmaf(wgt, f3.x, acc[6]); acc[7] = fmaf(wgt, f3.y, acc[7]);
}

// ---------------- conv2: aggregate G2h (1KB fp16 rows, 4-deep pipeline); h2=relu(+b2); G3h = h2 @ W3 ----------------
__global__ void conv2w_kernel(const __half* __restrict__ G2h, const float* __restrict__ dinv,
                              const int* __restrict__ rowptr, const int* __restrict__ csr_src,
                              const float* __restrict__ csr_norm, const float* __restrict__ b2,
                              const float* __restrict__ W3, __half* __restrict__ G3h) {
  __shared__ float h2s[4][512];
  int tid = threadIdx.x;
  int w = tid >> 6, l = tid & 63;
  int n0 = blockIdx.x * 4;
  int n = n0 + w;
  float di = dinv[n], dd = di * di;
  int e0 = rowptr[n], e1 = rowptr[n + 1];
  int cnt = e1 - e0 + 1;             // item 0 = self
  float acc[8] = {0, 0, 0, 0, 0, 0, 0, 0};
  int sm[4]; float wm[4];
  #pragma unroll
  for (int q = 0; q < 4; ++q) {
    int idx = q;
    if (idx == 0)       { sm[q] = n; wm[q] = dd; }
    else if (idx < cnt) { int e = e0 + idx - 1; sm[q] = csr_src[e]; wm[q] = csr_norm[e]; }
    else                { sm[q] = n; wm[q] = 0.f; }
  }
  for (int i = 0; i < cnt; i += 4) {
    uint4 r0 = *reinterpret_cast<const uint4*>(G2h + (size_t)sm[0] * 512 + l * 8);
    uint4 r1 = *reinterpret_cast<const uint4*>(G2h + (size_t)sm[1] * 512 + l * 8);
    uint4 r2 = *reinterpret_cast<const uint4*>(G2h + (size_t)sm[2] * 512 + l * 8);
    uint4 r3 = *reinterpret_cast<const uint4*>(G2h + (size_t)sm[3] * 512 + l * 8);
    float w0 = wm[0], w1 = wm[1], w2 = wm[2], w3 = wm[3];
    #pragma unroll
    for (int q = 0; q < 4; ++q) {
      int idx = i + 4 + q;           // >= 4, never self
      if (idx < cnt) { int e = e0 + idx - 1; sm[q] = csr_src[e]; wm[q] = csr_norm[e]; }
      else           { sm[q] = n; wm[q] = 0.f; }
    }
    accum8(acc, r0, w0);
    accum8(acc, r1, w1);
    accum8(acc, r2, w2);
    accum8(acc, r3, w3);
  }
  #pragma unroll
  for (int q = 0; q < 8; ++q)
    h2s[w][l * 8 + q] = fmaxf(acc[q] + b2[(l * 8 + q) & 63], 0.f);
  __syncthreads();
  // per-t dense: G3[t*64 + j] = sum_k h2[t*64+k] * W3[k][j]
  int t = tid >> 5;            // 0..7
  int jh = tid & 31, j0 = 2 * jh;
  float g[4][2];
  #pragma unroll
  for (int q = 0; q < 4; ++q) { g[q][0] = 0.f; g[q][1] = 0.f; }
  const float2* W3v = (const float2*)W3;
  for (int k = 0; k < 64; ++k) {
    float2 wv = W3v[k * 32 + jh];
    #pragma unroll
    for (int q = 0; q < 4; ++q) {
      float h = h2s[q][t * 64 + k];
      g[q][0] = fmaf(h, wv.x, g[q][0]);
      g[q][1] = fmaf(h, wv.y, g[q][1]);
    }
  }
  #pragma unroll
  for (int q = 0; q < 4; ++q) {
    __half2 hv;
    hv.x = __float2half_rn(g[q][0]);
    hv.y = __float2half_rn(g[q][1]);
    *reinterpret_cast<__half2*>(G3h + (size_t)(n0 + q) * 512 + t * 64 + j0) = hv;
  }
}

// ---------------- conv3 + head: aggregate G3h (4-deep); h3=relu(+b3); out = relu(h3@Wseq+bseq)@Wcls+bcls ----------------
__global__ void conv3w_kernel(const __half* __restrict__ G3h, const float* __restrict__ dinv,
                              const int* __restrict__ rowptr, const int* __restrict__ csr_src,
                              const float* __restrict__ csr_norm, const float* __restrict__ b3,
                              const float* __restrict__ Wseq, const float* __restrict__ bseq,
                              const float* __restrict__ Wcls, const float* __restrict__ bcls,
                              float* __restrict__ out) {
  __shared__ float h3s[4][512];
  __shared__ float red[4][4][64];
  __shared__ float hfs[4][64];
  int tid = threadIdx.x;
  int w = tid >> 6, l = tid & 63;
  int n0 = blockIdx.x * 4;
  int n = n0 + w;
  float di = dinv[n], dd = di * di;
  int e0 = rowptr[n], e1 = rowptr[n + 1];
  int cnt = e1 - e0 + 1;
  float acc[8] = {0, 0, 0, 0, 0, 0, 0, 0};
  int sm[4]; float wm[4];
  #pragma unroll
  for (int q = 0; q < 4; ++q) {
    int idx = q;
    if (idx == 0)       { sm[q] = n; wm[q] = dd; }
    else if (idx < cnt) { int e = e0 + idx - 1; sm[q] = csr_src[e]; wm[q] = csr_norm[e]; }
    else                { sm[q] = n; wm[q] = 0.f; }
  }
  for (int i = 0; i < cnt; i += 4) {
    uint4 r0 = *reinterpret_cast<const uint4*>(G3h + (size_t)sm[0] * 512 + l * 8);
    uint4 r1 = *reinterpret_cast<const uint4*>(G3h + (size_t)sm[1] * 512 + l * 8);
    uint4 r2 = *reinterpret_cast<const uint4*>(G3h + (size_t)sm[2] * 512 + l * 8);
    uint4 r3 = *reinterpret_cast<const uint4*>(G3h + (size_t)sm[3] * 512 + l * 8);
    float w0 = wm[0], w1 = wm[1], w2 = wm[2], w3 = wm[3];
    #pragma unroll
    for (int q = 0; q < 4; ++q) {
      int idx = i + 4 + q;
      if (idx < cnt) { int e = e0 + idx - 1; sm[q] = csr_src[e]; wm[q] = csr_norm[e]; }
      else           { sm[q] = n; wm[q] = 0.f; }
    }
    accum8(acc, r0, w0);
    accum8(acc, r1, w1);
    accum8(acc, r2, w2);
    accum8(acc, r3, w3);
  }
  #pragma unroll
  for (int q = 0; q < 8; ++q)
    h3s[w][l * 8 + q] = fmaxf(acc[q] + b3[(l * 8 + q) & 63], 0.f);
  __syncthreads();
  // seq contraction: partial[p][nb][j] = sum_{c in p-range} h3[nb][c] * Wseq[c][j]
  int p = tid >> 6, j = tid & 63;
  float pa0 = 0.f, pa1 = 0.f, pa2 = 0.f, pa3 = 0.f;
  for (int ci = 0; ci < 128; ++ci) {
    int c = p * 128 + ci;
    float wv = Wseq[(size_t)c * 64 + j];
    pa0 = fmaf(h3s[0][c], wv, pa0);
    pa1 = fmaf(h3s[1][c], wv, pa1);
    pa2 = fmaf(h3s[2][c], wv, pa2);
    pa3 = fmaf(h3s[3][c], wv, pa3);
  }
  red[p][0][j] = pa0; red[p][1][j] = pa1; red[p][2][j] = pa2; red[p][3][j] = pa3;
  __syncthreads();
  int nb = tid >> 6, k = tid & 63;
  float s = red[0][nb][k] + red[1][nb][k] + red[2][nb][k] + red[3][nb][k] + bseq[k];
  hfs[nb][k] = fmaxf(s, 0.f);
  __syncthreads();
  if (k < C) {
    float o = bcls[k];
    #pragma unroll
    for (int kk = 0; kk < 64; ++kk) o = fmaf(hfs[nb][kk], Wcls[kk * C + k], o);
    out[(size_t)(n0 + nb) * C + k] = o;
  }
}

// ================= NARROW FALLBACK (fp32, per-t) =================
__global__ void layer1N_kernel(const float* __restrict__ xagg, const float* __restrict__ W1,
                               const float* __restrict__ b1, const float* __restrict__ W2,
                               float* __restrict__ GA, int t) {
  __shared__ float hs[4][H];
  int tid = threadIdx.x;
  int wv = tid >> 6, j = tid & 63;
  int n = blockIdx.x * 4 + wv;
  const float* xa = xagg + (size_t)n * 128;
  float a = b1[j];
  #pragma unroll
  for (int f = 0; f < 16; ++f) a += xa[f * 8 + t] * W1[f * H + j];
  hs[wv][j] = fmaxf(a, 0.f);
  __syncthreads();
  float g = 0.f;
  #pragma unroll
  for (int k = 0; k < H; ++k) g += hs[wv][k] * W2[k * H + j];
  GA[(size_t)n * H + j] = g;
}

template<bool ACCUM>
__global__ void convN_kernel(const float* __restrict__ Gin, const float* __restrict__ dinv,
                             const int* __restrict__ rowptr, const int* __restrict__ csr_src,
                             const float* __restrict__ csr_norm, const float* __restrict__ b,
                             const float* __restrict__ Wnext, float* __restrict__ Gout) {
  __shared__ __align__(16) float hs[4][H];
  int tid = threadIdx.x;
  int wv = tid >> 6, lane = tid & 63;
  int sub = lane >> 4, q = lane & 15;
  int n = blockIdx.x * 4 + wv;
  float di = dinv[n];
  const float4* G4 = (const float4*)Gin;
  float4 a0 = {0,0,0,0}, a1 = {0,0,0,0};
  int e0 = rowptr[n], e1 = rowptr[n + 1];
  int e = e0 + sub;
  for (; e + 4 < e1; e += 8) {
    int s0 = csr_src[e];     float w0 = csr_norm[e];
    int s1 = csr_src[e + 4]; float w1 = csr_norm[e + 4];
    float4 r0 = G4[(size_t)s0 * 16 + q];
    float4 r1 = G4[(size_t)s1 * 16 + q];
    a0.x += w0 * r0.x; a0.y += w0 * r0.y; a0.z += w0 * r0.z; a0.w += w0 * r0.w;
    a1.x += w1 * r1.x; a1.y += w1 * r1.y; a1.z += w1 * r1.z; a1.w += w1 * r1.w;
  }
  for (; e < e1; e += 4) {
    int s0 = csr_src[e]; float w0 = csr_norm[e];
    float4 r0 = G4[(size_t)s0 * 16 + q];
    a0.x += w0 * r0.x; a0.y += w0 * r0.y; a0.z += w0 * r0.z; a0.w += w0 * r0.w;
  }
  a0.x += a1.x; a0.y += a1.y; a0.z += a1.z; a0.w += a1.w;
  #pragma unroll
  for (int off = 16; off <= 32; off <<= 1) {
    a0.x += __shfl_xor(a0.x, off, 64);
    a0.y += __shfl_xor(a0.y, off, 64);
    a0.z += __shfl_xor(a0.z, off, 64);
    a0.w += __shfl_xor(a0.w, off, 64);
  }
  float4 own = G4[(size_t)n * 16 + q];
  float dd = di * di;
  if (sub == 0) {
    float4 h;
    h.x = fmaxf(a0.x + dd * own.x + b[4 * q + 0], 0.f);
    h.y = fmaxf(a0.y + dd * own.y + b[4 * q + 1], 0.f);
    h.z = fmaxf(a0.z + dd * own.z + b[4 * q + 2], 0.f);
    h.w = fmaxf(a0.w + dd * own.w + b[4 * q + 3], 0.f);
    ((float4*)hs[wv])[q] = h;
  }
  __syncthreads();
  float g = 0.f;
  #pragma unroll
  for (int k = 0; k < H; ++k) g += hs[wv][k] * Wnext[k * H + lane];
  if (ACCUM) Gout[(size_t)n * H + lane] += g;
  else       Gout[(size_t)n * H + lane]  = g;
}

__global__ void final_kernel(const float* __restrict__ acc, const float* __restrict__ bseq,
                             const float* __restrict__ Wcls, const float* __restrict__ bcls,
                             float* __restrict__ out) {
  __shared__ float hs[4][H];
  int tid = threadIdx.x;
  int wv = tid >> 6, j = tid & 63;
  int n = blockIdx.x * 4 + wv;
  hs[wv][j] = fmaxf(acc[(size_t)n * H + j] + bseq[j], 0.0f);
  __syncthreads();
  if (j < C) {
    float o = bcls[j];
    #pragma unroll
    for (int k = 0; k < H; ++k) o += hs[wv][k] * Wcls[k * C + j];
    out[(size_t)n * C + j] = o;
  }
}

extern "C" void kernel_launch(void* const* d_in, const int* in_sizes, int n_in,
                              void* d_out, int out_size, void* d_ws, size_t ws_size,
                              hipStream_t stream) {
  const float* x    = (const float*)d_in[0];
  const int*   ei   = (const int*)  d_in[1];
  const float* w    = (const float*)d_in[2];
  const float* W1   = (const float*)d_in[3];
  const float* b1   = (const float*)d_in[4];
  const float* W2   = (const float*)d_in[5];
  const float* b2   = (const float*)d_in[6];
  const float* W3   = (const float*)d_in[7];
  const float* b3   = (const float*)d_in[8];
  const float* Wseq = (const float*)d_in[9];
  const float* bseq = (const float*)d_in[10];
  const float* Wcls = (const float*)d_in[11];
  const float* bcls = (const float*)d_in[12];
  float* out = (float*)d_out;

  char* p = (char*)d_ws;
  auto alloc = [&](size_t bytes) -> char* {
    char* r = p; p += (bytes + 255) & ~(size_t)255; return r;
  };
  float*  deg     = (float*) alloc((size_t)N * 4);      // becomes dinv
  int*    counts  = (int*)   alloc((size_t)N * 4);
  int*    fillc   = (int*)   alloc((size_t)N * 4);
  int*    rowptr  = (int*)   alloc((size_t)(N + 1) * 4);
  int*    csr_src = (int*)   alloc((size_t)E * 4);
  float*  csr_nrm = (float*) alloc((size_t)E * 4);
  float*  xagg    = (float*) alloc((size_t)N * 128 * 4);
  __half* xh      = (__half*)alloc((size_t)N * 128 * 2);

  hipMemsetAsync(deg,    0, (size_t)N * 4, stream);
  hipMemsetAsync(counts, 0, (size_t)N * 4, stream);
  hipMemsetAsync(fillc,  0, (size_t)N * 4, stream);

  cvt_x_kernel<<<(N * 32 + 255) / 256, 256, 0, stream>>>(x, xh);
  deg_count_kernel<<<(E + 255) / 256, 256, 0, stream>>>(ei, w, deg, counts);
  dinv_kernel<<<(N + 255) / 256, 256, 0, stream>>>(deg);
  scan_kernel<<<1, 1024, 0, stream>>>(counts, rowptr);
  fill_kernel<<<(E + 255) / 256, 256, 0, stream>>>(ei, w, deg, rowptr, fillc, csr_src, csr_nrm);
  agg_x_kernel<<<N / 4, 256, 0, stream>>>(xh, deg, rowptr, csr_src, csr_nrm, xagg);

  // wide needs: common 52MB + G2h 51.2MB + G3h 51.2MB ~= 154.6MB
  bool wide = ws_size >= (size_t)155 * 1000 * 1000;

  if (wide) {
    __half* G2h = (__half*)alloc((size_t)N * 512 * 2);
    __half* G3h = (__half*)alloc((size_t)N * 512 * 2);
    dense12_kernel<<<N / 4, 256, 0, stream>>>(xagg, W1, b1, W2, G2h);
    conv2w_kernel<<<N / 4, 256, 0, stream>>>(G2h, deg, rowptr, csr_src, csr_nrm, b2, W3, G3h);
    conv3w_kernel<<<N / 4, 256, 0, stream>>>(G3h, deg, rowptr, csr_src, csr_nrm, b3,
                                             Wseq, bseq, Wcls, bcls, out);
  } else {
    float* GA  = (float*)alloc((size_t)N * H * 4);
    float* GB  = (float*)alloc((size_t)N * H * 4);
    float* acc = (float*)alloc((size_t)N * H * 4);
    hipMemsetAsync(acc, 0, (size_t)N * H * 4, stream);
    for (int t = 0; t < T; ++t) {
      layer1N_kernel<<<N / 4, 256, 0, stream>>>(xagg, W1, b1, W2, GA, t);
      convN_kernel<false><<<N / 4, 256, 0, stream>>>(GA, deg, rowptr, csr_src, csr_nrm, b2, W3, GB);
      convN_kernel<true ><<<N / 4, 256, 0, stream>>>(GB, deg, rowptr, csr_src, csr_nrm, b3,
                                                     Wseq + (size_t)t * H * H, acc);
    }
    final_kernel<<<N / 4, 256, 0, stream>>>(acc, bseq, Wcls, bcls, out);
  }
}